// Round 5
// baseline (481.352 us; speedup 1.0000x reference)
//
#include <hip/hip_runtime.h>

#define NG   4096
#define P    24
#define EPG  192
#define ESL  216
#define DIN  32
#define H    128
#define EX   8
#define NOUT 3
#define HSS  136   // f16 row stride for [24][H] tiles (272B rows)
#define XTS  36    // xlT row stride in ushorts (72B rows)
#define AMS  36    // Am row stride in f32 (144B rows; breaks 128B periodicity)

typedef _Float16 f16x8 __attribute__((ext_vector_type(8)));
typedef _Float16 h2    __attribute__((ext_vector_type(2)));
typedef float    f32x4 __attribute__((ext_vector_type(4)));

__device__ __forceinline__ unsigned short f2h(float v) {
    _Float16 h = (_Float16)v; unsigned short u; __builtin_memcpy(&u, &h, 2); return u;
}
__device__ __forceinline__ float h2f(unsigned short u) {
    _Float16 h; __builtin_memcpy(&h, &u, 2); return (float)h;
}
__device__ __forceinline__ unsigned pkadd(unsigned a, unsigned b) {
    h2 x, y; __builtin_memcpy(&x, &a, 4); __builtin_memcpy(&y, &b, 4);
    h2 z = x + y; unsigned r; __builtin_memcpy(&r, &z, 4); return r;
}
__device__ __forceinline__ float lrelu(float v, float s) { return v > 0.f ? v : v * s; }

// paired b32 store: even lane stores (self | neighbor<<16). DPP quad_perm [1,0,3,2]
// = lane^1 exchange, VALU-only (no LDS pipe). Caller guarantees pair-uniform exec.
#define STPAIR(BASE, ROW, COL, VAL)                                           \
    do {                                                                      \
        unsigned o_ = (unsigned)__builtin_amdgcn_mov_dpp(                     \
            (int)(unsigned)(VAL), 0xB1, 0xF, 0xF, true);                      \
        if (!(lane & 1))                                                      \
            *reinterpret_cast<unsigned*>(&(BASE)[(ROW) * HSS + (COL)]) =      \
                (unsigned)(VAL) | (o_ << 16);                                 \
    } while (0)

// ---- prepass: convert/transpose weights to f16 in d_ws (ushort elems) ----
// W0T[128][32]@0 | W1T[128][128]@4096 | WLT[6][128][128]@20480 | WRT@118784
// WAL[6][16][128]@217088 (row0 = Wl@att) | WAR[6][16][128]@229376
// f32 consts @ushort 241664: bla[6], bra[6]
__global__ void cvtw(const float* __restrict__ W0, const float* __restrict__ W1,
                     const float* __restrict__ Wl, const float* __restrict__ Wr,
                     const float* __restrict__ att, const float* __restrict__ bl,
                     const float* __restrict__ br, unsigned short* __restrict__ ws) {
    int i = blockIdx.x * 256 + threadIdx.x;
    if (i < 217088) {
        float v;
        if (i < 4096)        { int n = i >> 5, k = i & 31;  v = W0[k * 128 + n]; }
        else if (i < 20480)  { int j = i - 4096;  int n = j >> 7, k = j & 127; v = W1[k * 128 + n]; }
        else if (i < 118784) { int j = i - 20480; int c = j >> 14, r = j & 16383;
                               int n = r >> 7, k = r & 127; v = Wl[c * 16384 + k * 128 + n]; }
        else                 { int j = i - 118784; int c = j >> 14, r = j & 16383;
                               int n = r >> 7, k = r & 127; v = Wr[c * 16384 + k * 128 + n]; }
        ws[i] = f2h(v);
    } else if (i < 241664) {
        int j = i - 217088;
        const float* W = (j < 12288) ? Wl : Wr;
        if (j >= 12288) j -= 12288;
        int c = j >> 11, r = j & 2047, row = r >> 7, k = r & 127;
        float v = 0.f;
        if (row == 0) {
            for (int q = 0; q < 128; ++q) v += W[c * 16384 + k * 128 + q] * att[c * 128 + q];
        }
        ws[i] = f2h(v);
    } else if (i < 241676) {
        int c = i - 241664;
        const float* B = (c < 6) ? bl : br;
        int cc = (c < 6) ? c : c - 6;
        float s = 0.f;
        for (int q = 0; q < 128; ++q) s += B[cc * 128 + q] * att[cc * 128 + q];
        ((float*)(ws + 241664))[c] = s;
    }
}

__global__ __launch_bounds__(256, 5) void gat_all(
    const float* __restrict__ x,
    const int*   __restrict__ src,
    const int*   __restrict__ dst,
    const float* __restrict__ extra,
    const float* __restrict__ b0,  const float* __restrict__ b1,
    const float* __restrict__ bl,  const float* __restrict__ br,
    const float* __restrict__ att, const float* __restrict__ cbias,
    const float* __restrict__ Wf0, const float* __restrict__ bf0,
    const float* __restrict__ Wf1, const float* __restrict__ bf1,
    const float* __restrict__ Wf2, const float* __restrict__ bf2,
    const unsigned short* __restrict__ wsb,
    float* __restrict__ out)
{
    // exactly 32768 B -> 5 blocks/CU. Flat block so benign pad-row over-reads
    // (rows 24-31, feeding only suppressed stores) stay inside allocated LDS.
    __shared__ __align__(16) unsigned char LDSM[32768];
    unsigned short* hb  = (unsigned short*)(LDSM);           // [24][HSS] 6528 B
    unsigned short* xlb = (unsigned short*)(LDSM + 6528);    // [24][HSS] 6528 B
    unsigned short* xrb = (unsigned short*)(LDSM + 13056);   // [24][HSS] 6528 B
    unsigned short* xlT = (unsigned short*)(LDSM + 19584);   // [128][XTS] 9216 B
    float*          Am  = (float*)(LDSM + 28800);            // [24][AMS] 3456 B
    float*          sn  = (float*)(LDSM + 32256);            // snode: sl[0..31] sr[32..63]
    unsigned int*   ath = (unsigned int*)(LDSM + 32512);     // att packed f16 pairs, 256 B

    const int g    = blockIdx.x;
    const int t    = threadIdx.x;
    const int lane = t & 63;
    const int w    = t >> 6;
    const int m16  = lane & 15;
    const int kc   = lane >> 4;
    const long long gn = (long long)g * P;

    const unsigned short* W0T = wsb;
    const unsigned short* W1T = wsb + 4096;
    const unsigned short* WLT = wsb + 20480;
    const unsigned short* WRT = wsb + 118784;
    const float* wsf = (const float*)(wsb + 241664);

    int s_e = 0, d_e = 0;
    if (t < ESL) {
        if (t < EPG) {
            s_e = src[(long long)g * EPG + t] - (int)gn;
            d_e = dst[(long long)g * EPG + t] - (int)gn;
        } else { s_e = d_e = t - EPG; }
    }

    // stage x (f16) into xlT as [32 nodes][32 feat], stride XTS (rows 24-31 zero)
    if (t < 192) {
        float4 v = *reinterpret_cast<const float4*>(&x[gn * DIN + t * 4]);
        int n = t >> 3, k = (t & 7) * 4;
        *reinterpret_cast<ushort4*>(&xlT[n * XTS + k]) =
            make_ushort4(f2h(v.x), f2h(v.y), f2h(v.z), f2h(v.w));
    } else {
        int u = t - 192;
        int r = 24 + (u >> 3), k = (u & 7) * 4;
        *reinterpret_cast<ushort4*>(&xlT[r * XTS + k]) = make_ushort4(0, 0, 0, 0);
    }
    __syncthreads();

    // ---------------- init MLP layer 0: xlb = LR(x @ W0 + b0) ----------------
    {
        f32x4 acc[4] = {};
        f16x8 a = *reinterpret_cast<const f16x8*>(&xlT[((w & 1) * 16 + m16) * XTS + kc * 8]);
        #pragma unroll
        for (int i = 0; i < 4; ++i) {
            int nt = (w >> 1) * 4 + i;
            f16x8 b = *reinterpret_cast<const f16x8*>(&W0T[(nt * 16 + m16) * 32 + kc * 8]);
            acc[i] = __builtin_amdgcn_mfma_f32_16x16x32_f16(a, b, acc[i], 0, 0, 0);
        }
        const bool live = !((w & 1) && kc >= 2);   // rows >= 24 suppressed
        if (live) {
            #pragma unroll
            for (int i = 0; i < 4; ++i) {
                int col = (w >> 1) * 64 + i * 16 + m16;
                float bv = b0[col];
                #pragma unroll
                for (int r = 0; r < 4; ++r) {
                    int row = (w & 1) * 16 + kc * 4 + r;
                    unsigned short ub = f2h(lrelu(acc[i][r] + bv, 0.01f));
                    STPAIR(xlb, row, col, ub);
                }
            }
        }
    }
    __syncthreads();

    // ---------------- init MLP layer 1: hb = LR(xlb @ W1 + b1) ---------------
    {
        f32x4 acc[4] = {};
        for (int kt = 0; kt < 4; ++kt) {
            f16x8 a = *reinterpret_cast<const f16x8*>(&xlb[((w & 1) * 16 + m16) * HSS + kt * 32 + kc * 8]);
            #pragma unroll
            for (int i = 0; i < 4; ++i) {
                int nt = (w >> 1) * 4 + i;
                f16x8 b = *reinterpret_cast<const f16x8*>(&W1T[(nt * 16 + m16) * 128 + kt * 32 + kc * 8]);
                acc[i] = __builtin_amdgcn_mfma_f32_16x16x32_f16(a, b, acc[i], 0, 0, 0);
            }
        }
        const bool live = !((w & 1) && kc >= 2);
        if (live) {
            #pragma unroll
            for (int i = 0; i < 4; ++i) {
                int col = (w >> 1) * 64 + i * 16 + m16;
                float bv = b1[col];
                #pragma unroll
                for (int r = 0; r < 4; ++r) {
                    int row = (w & 1) * 16 + kc * 4 + r;
                    unsigned short ub = f2h(lrelu(acc[i][r] + bv, 0.01f));
                    STPAIR(hb, row, col, ub);
                }
            }
        }
    }
    __syncthreads();

    // ---------------- 6 GATv2 convs (3 barriers each) ----------------
    for (int c = 0; c < 6; ++c) {
        if (t < ESL) *reinterpret_cast<float4*>(&Am[t * 4]) = make_float4(0.f, 0.f, 0.f, 0.f);
        if (t < 64) ath[t] = ((unsigned)f2h(att[c * H + 2 * t])) |
                             (((unsigned)f2h(att[c * H + 2 * t + 1])) << 16);

        // xl = hb@Wl + bl / xr = hb@Wr + br  (wave parity picks matrix)
        const unsigned short* WT   = ((w & 1) ? WRT : WLT) + c * 16384;
        const unsigned short* WAX  = wsb + 217088 + ((w & 1) ? 12288 : 0) + c * 2048;
        const float*          bias = ((w & 1) ? br : bl) + c * H;
        f32x4 acc[8] = {};
        f32x4 acce[2] = {};
        for (int kt = 0; kt < 4; ++kt) {
            f16x8 a0 = *reinterpret_cast<const f16x8*>(&hb[(m16)      * HSS + kt * 32 + kc * 8]);
            f16x8 a1 = *reinterpret_cast<const f16x8*>(&hb[(16 + m16) * HSS + kt * 32 + kc * 8]);
            #pragma unroll
            for (int i = 0; i < 4; ++i) {
                int nt = (w >> 1) * 4 + i;
                f16x8 b = *reinterpret_cast<const f16x8*>(&WT[(nt * 16 + m16) * 128 + kt * 32 + kc * 8]);
                acc[i]     = __builtin_amdgcn_mfma_f32_16x16x32_f16(a0, b, acc[i],     0, 0, 0);
                acc[4 + i] = __builtin_amdgcn_mfma_f32_16x16x32_f16(a1, b, acc[4 + i], 0, 0, 0);
            }
            if (w >= 2) {   // sl/sr tile: B row0 = W@att, rows 1-15 zero
                f16x8 bx = *reinterpret_cast<const f16x8*>(&WAX[m16 * 128 + kt * 32 + kc * 8]);
                acce[0] = __builtin_amdgcn_mfma_f32_16x16x32_f16(a0, bx, acce[0], 0, 0, 0);
                acce[1] = __builtin_amdgcn_mfma_f32_16x16x32_f16(a1, bx, acce[1], 0, 0, 0);
            }
        }
        {
            unsigned short* XO = (w & 1) ? xrb : xlb;
            const bool isL = !(w & 1);
            #pragma unroll
            for (int mt = 0; mt < 2; ++mt) {
                const bool live = !(mt == 1 && kc >= 2);   // rows >= 24
                if (live) {
                    #pragma unroll
                    for (int i = 0; i < 4; ++i) {
                        int col = (w >> 1) * 64 + i * 16 + m16;
                        float bv = bias[col];
                        unsigned short ub[4];
                        #pragma unroll
                        for (int r = 0; r < 4; ++r) {
                            int row = mt * 16 + kc * 4 + r;
                            ub[r] = f2h(acc[mt * 4 + i][r] + bv);
                            STPAIR(XO, row, col, ub[r]);
                        }
                        if (isL)
                            *reinterpret_cast<ushort4*>(&xlT[col * XTS + mt * 16 + kc * 4]) =
                                make_ushort4(ub[0], ub[1], ub[2], ub[3]);
                    }
                }
            }
            if (w >= 2 && m16 == 0) {       // col 0 of the slr tile = sl/sr
                float cst = (w == 2) ? wsf[c] : wsf[6 + c];
                float* dp = (w == 2) ? sn : (sn + 32);
                #pragma unroll
                for (int mt = 0; mt < 2; ++mt)
                #pragma unroll
                for (int r = 0; r < 4; ++r)
                    dp[mt * 16 + kc * 4 + r] = acce[mt][r] + cst;
            }
        }
        __syncthreads();

        // phase 2: per-edge logit + exp + scatter (unnormalized ex into Am)
        if (t < ESL) {
            const uint4* xa = reinterpret_cast<const uint4*>(&xlb[s_e * HSS]);
            const uint4* xb = reinterpret_cast<const uint4*>(&xrb[d_e * HSS]);
            const uint4* ap = reinterpret_cast<const uint4*>(ath);
            float a0 = 0.f, a1 = 0.f, a2 = 0.f, a3 = 0.f;
            #pragma unroll 4
            for (int cc = 0; cc < 16; ++cc) {
                uint4 wa = xa[cc], wb = xb[cc], pp = ap[cc];
                unsigned u0 = pkadd(wa.x, wb.x) & 0x7fff7fffu;
                unsigned u1 = pkadd(wa.y, wb.y) & 0x7fff7fffu;
                unsigned u2 = pkadd(wa.z, wb.z) & 0x7fff7fffu;
                unsigned u3 = pkadd(wa.w, wb.w) & 0x7fff7fffu;
                asm volatile("v_dot2_f32_f16 %0, %1, %2, %0" : "+v"(a0) : "v"(u0), "v"(pp.x));
                asm volatile("v_dot2_f32_f16 %0, %1, %2, %0" : "+v"(a1) : "v"(u1), "v"(pp.y));
                asm volatile("v_dot2_f32_f16 %0, %1, %2, %0" : "+v"(a2) : "v"(u2), "v"(pp.z));
                asm volatile("v_dot2_f32_f16 %0, %1, %2, %0" : "+v"(a3) : "v"(u3), "v"(pp.w));
            }
            float abss = (a0 + a1) + (a2 + a3);
            float lg = fmaf(0.6f, sn[s_e] + sn[32 + d_e], 0.4f * abss);
            atomicAdd(&Am[d_e * AMS + s_e], __expf(lg));
        }
        __syncthreads();

        // phase 3: aggregate hb = (rowscale(Am) @ xl) + cbias (+ LR except convs 2,5)
        {
            int arow = (w & 1) * 16 + m16;
            float4 u0, u1;
            if (arow < P) {
                u0 = *reinterpret_cast<const float4*>(&Am[arow * AMS + kc * 8]);
                u1 = *reinterpret_cast<const float4*>(&Am[arow * AMS + kc * 8 + 4]);
            } else {
                u0 = make_float4(0.f, 0.f, 0.f, 0.f);
                u1 = u0;
            }
            float rs = u0.x + u0.y + u0.z + u0.w + u1.x + u1.y + u1.z + u1.w;
            rs += __shfl_xor(rs, 16);
            rs += __shfl_xor(rs, 32);
            float sc = (arow < P) ? __builtin_amdgcn_rcpf(rs) : 0.f;
            f16x8 a;
            a[0] = (_Float16)(u0.x * sc); a[1] = (_Float16)(u0.y * sc);
            a[2] = (_Float16)(u0.z * sc); a[3] = (_Float16)(u0.w * sc);
            a[4] = (_Float16)(u1.x * sc); a[5] = (_Float16)(u1.y * sc);
            a[6] = (_Float16)(u1.z * sc); a[7] = (_Float16)(u1.w * sc);
            f32x4 acc2[4] = {};
            #pragma unroll
            for (int i = 0; i < 4; ++i) {
                int nt = (w >> 1) * 4 + i;
                f16x8 b = *reinterpret_cast<const f16x8*>(&xlT[(nt * 16 + m16) * XTS + kc * 8]);
                acc2[i] = __builtin_amdgcn_mfma_f32_16x16x32_f16(a, b, acc2[i], 0, 0, 0);
            }
            const bool doact = (c % 3) < 2;
            const bool live = !((w & 1) && kc >= 2);
            if (live) {
                #pragma unroll
                for (int i = 0; i < 4; ++i) {
                    int col = (w >> 1) * 64 + i * 16 + m16;
                    float cb = cbias[c * H + col];
                    #pragma unroll
                    for (int r = 0; r < 4; ++r) {
                        int row = (w & 1) * 16 + kc * 4 + r;
                        float v = acc2[i][r] + cb;
                        if (doact) v = lrelu(v, 0.01f);
                        unsigned short ub = f2h(v);
                        STPAIR(hb, row, col, ub);
                    }
                }
            }
        }
        __syncthreads();
    }

    // ---------------- pool + head MLP (f32, xlb region reused as scratch) ----
    float* scr = (float*)(LDSM + 6528);
    float* z  = scr;          // 136
    float* pa = scr + 144;
    float* pb = scr + 288;
    float* h1 = scr + 432;
    float* qa = scr + 576;
    float* qb = scr + 720;
    float* h2 = scr + 864;    // ends at 992 floats < 1632 available
    if (t < H) {
        float s = 0.f;
        for (int r = 0; r < P; ++r) s += h2f(hb[r * HSS + t]);
        z[t] = s;
    } else if (t < H + EX) {
        z[t] = extra[(long long)g * EX + (t - H)];
    }
    __syncthreads();
    {
        int j = t & 127, half = t >> 7;
        float a = half ? 0.f : bf0[j];
        int k0 = half ? 68 : 0, k1 = half ? 136 : 68;
        for (int k = k0; k < k1; ++k) a += z[k] * Wf0[k * H + j];
        (half ? pb : pa)[j] = a;
    }
    __syncthreads();
    if (t < H) h1[t] = lrelu(pa[t] + pb[t], 0.01f);
    __syncthreads();
    {
        int j = t & 127, half = t >> 7;
        float a = half ? 0.f : bf1[j];
        int k0 = half * 64, k1 = k0 + 64;
        for (int k = k0; k < k1; ++k) a += h1[k] * Wf1[k * H + j];
        (half ? qb : qa)[j] = a;
    }
    __syncthreads();
    if (t < H) h2[t] = lrelu(qa[t] + qb[t], 0.01f);
    __syncthreads();
    if (t < NOUT) {
        float a = bf2[t];
        for (int k = 0; k < H; ++k) a += h2[k] * Wf2[k * NOUT + t];
        out[(long long)g * NOUT + t] = a;
    }
}

extern "C" void kernel_launch(void* const* d_in, const int* in_sizes, int n_in,
                              void* d_out, int out_size, void* d_ws, size_t ws_size,
                              hipStream_t stream) {
    (void)in_sizes; (void)n_in; (void)out_size; (void)ws_size;
    const float* x     = (const float*)d_in[0];
    const int*   src   = (const int*)  d_in[1];
    const int*   dst   = (const int*)  d_in[2];
    const float* extra = (const float*)d_in[4];
    const float* W0    = (const float*)d_in[5];
    const float* b0    = (const float*)d_in[6];
    const float* W1    = (const float*)d_in[7];
    const float* b1    = (const float*)d_in[8];
    const float* Wl    = (const float*)d_in[9];
    const float* bl    = (const float*)d_in[10];
    const float* Wr    = (const float*)d_in[11];
    const float* br    = (const float*)d_in[12];
    const float* att   = (const float*)d_in[13];
    const float* cbias = (const float*)d_in[14];
    const float* Wf0   = (const float*)d_in[15];
    const float* bf0   = (const float*)d_in[16];
    const float* Wf1   = (const float*)d_in[17];
    const float* bf1   = (const float*)d_in[18];
    const float* Wf2   = (const float*)d_in[19];
    const float* bf2   = (const float*)d_in[20];
    unsigned short* wsb = (unsigned short*)d_ws;
    float* out = (float*)d_out;

    cvtw<<<945, 256, 0, stream>>>(W0, W1, Wl, Wr, att, bl, br, wsb);
    gat_all<<<NG, 256, 0, stream>>>(x, src, dst, extra, b0, b1, bl, br, att, cbias,
                                    Wf0, bf0, Wf1, bf1, Wf2, bf2, wsb, out);
}

// Round 7
// 380.192 us; speedup vs baseline: 1.2661x; 1.2661x over previous
//
#include <hip/hip_runtime.h>

#define NG   4096
#define P    24
#define EPG  192
#define ESL  216
#define DIN  32
#define H    128
#define EX   8
#define NOUT 3
#define HSS  136   // f16 row stride for [24][H] tiles (272B rows)
#define XTS  36    // xlT row stride in ushorts (72B rows)
#define AMS  36    // Am row stride in f32 (144B rows; breaks 128B periodicity)

typedef _Float16 f16x8 __attribute__((ext_vector_type(8)));
typedef _Float16 h2    __attribute__((ext_vector_type(2)));
typedef float    f32x4 __attribute__((ext_vector_type(4)));

__device__ __forceinline__ unsigned short f2h(float v) {
    _Float16 h = (_Float16)v; unsigned short u; __builtin_memcpy(&u, &h, 2); return u;
}
__device__ __forceinline__ float h2f(unsigned short u) {
    _Float16 h; __builtin_memcpy(&h, &u, 2); return (float)h;
}
__device__ __forceinline__ unsigned pkadd(unsigned a, unsigned b) {
    h2 x, y; __builtin_memcpy(&x, &a, 4); __builtin_memcpy(&y, &b, 4);
    h2 z = x + y; unsigned r; __builtin_memcpy(&r, &z, 4); return r;
}
__device__ __forceinline__ float lrelu(float v, float s) { return v > 0.f ? v : v * s; }

// paired b32 store: even lane stores (self | neighbor<<16). DPP quad_perm [1,0,3,2]
// = lane^1 exchange, VALU-only (no LDS pipe). Caller guarantees pair-uniform exec.
#define STPAIR(BASE, ROW, COL, VAL)                                           \
    do {                                                                      \
        unsigned o_ = (unsigned)__builtin_amdgcn_mov_dpp(                     \
            (int)(unsigned)(VAL), 0xB1, 0xF, 0xF, true);                      \
        if (!(lane & 1))                                                      \
            *reinterpret_cast<unsigned*>(&(BASE)[(ROW) * HSS + (COL)]) =      \
                (unsigned)(VAL) | (o_ << 16);                                 \
    } while (0)

// ---- prepass: convert/transpose weights to f16 in d_ws (ushort elems) ----
// W0T[128][32]@0 | W1T[128][128]@4096 | WLT[6][128][128]@20480 | WRT@118784
// WAL[6][16][128]@217088 (row0 = Wl@att) | WAR[6][16][128]@229376
// f32 consts @ushort 241664: bla[6], bra[6]
__global__ void cvtw(const float* __restrict__ W0, const float* __restrict__ W1,
                     const float* __restrict__ Wl, const float* __restrict__ Wr,
                     const float* __restrict__ att, const float* __restrict__ bl,
                     const float* __restrict__ br, unsigned short* __restrict__ ws) {
    int i = blockIdx.x * 256 + threadIdx.x;
    if (i < 217088) {
        float v;
        if (i < 4096)        { int n = i >> 5, k = i & 31;  v = W0[k * 128 + n]; }
        else if (i < 20480)  { int j = i - 4096;  int n = j >> 7, k = j & 127; v = W1[k * 128 + n]; }
        else if (i < 118784) { int j = i - 20480; int c = j >> 14, r = j & 16383;
                               int n = r >> 7, k = r & 127; v = Wl[c * 16384 + k * 128 + n]; }
        else                 { int j = i - 118784; int c = j >> 14, r = j & 16383;
                               int n = r >> 7, k = r & 127; v = Wr[c * 16384 + k * 128 + n]; }
        ws[i] = f2h(v);
    } else if (i < 241664) {
        int j = i - 217088;
        const float* W = (j < 12288) ? Wl : Wr;
        if (j >= 12288) j -= 12288;
        int c = j >> 11, r = j & 2047, row = r >> 7, k = r & 127;
        float v = 0.f;
        if (row == 0) {
            for (int q = 0; q < 128; ++q) v += W[c * 16384 + k * 128 + q] * att[c * 128 + q];
        }
        ws[i] = f2h(v);
    } else if (i < 241676) {
        int c = i - 241664;
        const float* B = (c < 6) ? bl : br;
        int cc = (c < 6) ? c : c - 6;
        float s = 0.f;
        for (int q = 0; q < 128; ++q) s += B[cc * 128 + q] * att[cc * 128 + q];
        ((float*)(ws + 241664))[c] = s;
    }
}

__global__ __launch_bounds__(256, 4) void gat_all(
    const float* __restrict__ x,
    const int*   __restrict__ src,
    const int*   __restrict__ dst,
    const float* __restrict__ extra,
    const float* __restrict__ b0,  const float* __restrict__ b1,
    const float* __restrict__ bl,  const float* __restrict__ br,
    const float* __restrict__ att, const float* __restrict__ cbias,
    const float* __restrict__ Wf0, const float* __restrict__ bf0,
    const float* __restrict__ Wf1, const float* __restrict__ bf1,
    const float* __restrict__ Wf2, const float* __restrict__ bf2,
    const unsigned short* __restrict__ wsb,
    float* __restrict__ out)
{
    // 32768 B LDS. Flat block so benign pad-row over-READS (rows 24-31 of hb,
    // feeding only suppressed stores / MFMA row-independent lanes) stay inside
    // allocated LDS. xlT node entries 24-31 are explicitly ZEROED (read as
    // B-frag K-tail where 0*NaN would poison real rows — R6 bug).
    __shared__ __align__(16) unsigned char LDSM[32768];
    unsigned short* hb  = (unsigned short*)(LDSM);           // [24][HSS] 6528 B
    unsigned short* xlb = (unsigned short*)(LDSM + 6528);    // [24][HSS] 6528 B
    unsigned short* xrb = (unsigned short*)(LDSM + 13056);   // [24][HSS] 6528 B
    unsigned short* xlT = (unsigned short*)(LDSM + 19584);   // [128][XTS] 9216 B
    float*          Am  = (float*)(LDSM + 28800);            // [24][AMS] 3456 B
    float*          sn  = (float*)(LDSM + 32256);            // snode: sl[0..31] sr[32..63]
    unsigned int*   ath = (unsigned int*)(LDSM + 32512);     // att packed f16 pairs, 256 B

    const int g    = blockIdx.x;
    const int t    = threadIdx.x;
    const int lane = t & 63;
    const int w    = t >> 6;
    const int m16  = lane & 15;
    const int kc   = lane >> 4;
    const long long gn = (long long)g * P;

    const unsigned short* W0T = wsb;
    const unsigned short* W1T = wsb + 4096;
    const unsigned short* WLT = wsb + 20480;
    const unsigned short* WRT = wsb + 118784;
    const float* wsf = (const float*)(wsb + 241664);

    int s_e = 0, d_e = 0;
    if (t < ESL) {
        if (t < EPG) {
            s_e = src[(long long)g * EPG + t] - (int)gn;
            d_e = dst[(long long)g * EPG + t] - (int)gn;
        } else { s_e = d_e = t - EPG; }
    }

    // stage x (f16) into xlT as [32 nodes][32 feat], stride XTS (rows 24-31 zero)
    if (t < 192) {
        float4 v = *reinterpret_cast<const float4*>(&x[gn * DIN + t * 4]);
        int n = t >> 3, k = (t & 7) * 4;
        *reinterpret_cast<ushort4*>(&xlT[n * XTS + k]) =
            make_ushort4(f2h(v.x), f2h(v.y), f2h(v.z), f2h(v.w));
    } else {
        int u = t - 192;
        int r = 24 + (u >> 3), k = (u & 7) * 4;
        *reinterpret_cast<ushort4*>(&xlT[r * XTS + k]) = make_ushort4(0, 0, 0, 0);
    }
    __syncthreads();

    // ---------------- init MLP layer 0: xlb = LR(x @ W0 + b0) ----------------
    {
        f32x4 acc[4] = {};
        f16x8 a = *reinterpret_cast<const f16x8*>(&xlT[((w & 1) * 16 + m16) * XTS + kc * 8]);
        #pragma unroll
        for (int i = 0; i < 4; ++i) {
            int nt = (w >> 1) * 4 + i;
            f16x8 b = *reinterpret_cast<const f16x8*>(&W0T[(nt * 16 + m16) * 32 + kc * 8]);
            acc[i] = __builtin_amdgcn_mfma_f32_16x16x32_f16(a, b, acc[i], 0, 0, 0);
        }
        const bool live = !((w & 1) && kc >= 2);   // rows >= 24 suppressed
        if (live) {
            #pragma unroll
            for (int i = 0; i < 4; ++i) {
                int col = (w >> 1) * 64 + i * 16 + m16;
                float bv = b0[col];
                #pragma unroll
                for (int r = 0; r < 4; ++r) {
                    int row = (w & 1) * 16 + kc * 4 + r;
                    unsigned short ub = f2h(lrelu(acc[i][r] + bv, 0.01f));
                    STPAIR(xlb, row, col, ub);
                }
            }
        }
    }
    __syncthreads();

    // ---------------- init MLP layer 1: hb = LR(xlb @ W1 + b1) ---------------
    // xlT is dead here (x consumed, transposed data not yet written): zero the
    // WHOLE conv-layout region so B-frag K=24..31 reads are exactly 0 forever.
    {
        unsigned* xz = reinterpret_cast<unsigned*>(xlT);
        #pragma unroll
        for (int i = 0; i < 9; ++i) xz[t + i * 256] = 0u;   // 2304 dwords = 9216 B
        f32x4 acc[4] = {};
        for (int kt = 0; kt < 4; ++kt) {
            f16x8 a = *reinterpret_cast<const f16x8*>(&xlb[((w & 1) * 16 + m16) * HSS + kt * 32 + kc * 8]);
            #pragma unroll
            for (int i = 0; i < 4; ++i) {
                int nt = (w >> 1) * 4 + i;
                f16x8 b = *reinterpret_cast<const f16x8*>(&W1T[(nt * 16 + m16) * 128 + kt * 32 + kc * 8]);
                acc[i] = __builtin_amdgcn_mfma_f32_16x16x32_f16(a, b, acc[i], 0, 0, 0);
            }
        }
        const bool live = !((w & 1) && kc >= 2);
        if (live) {
            #pragma unroll
            for (int i = 0; i < 4; ++i) {
                int col = (w >> 1) * 64 + i * 16 + m16;
                float bv = b1[col];
                #pragma unroll
                for (int r = 0; r < 4; ++r) {
                    int row = (w & 1) * 16 + kc * 4 + r;
                    unsigned short ub = f2h(lrelu(acc[i][r] + bv, 0.01f));
                    STPAIR(hb, row, col, ub);
                }
            }
        }
    }
    __syncthreads();

    // ---------------- 6 GATv2 convs (3 barriers each) ----------------
    for (int c = 0; c < 6; ++c) {
        if (t < ESL) *reinterpret_cast<float4*>(&Am[t * 4]) = make_float4(0.f, 0.f, 0.f, 0.f);
        if (t < 64) ath[t] = ((unsigned)f2h(att[c * H + 2 * t])) |
                             (((unsigned)f2h(att[c * H + 2 * t + 1])) << 16);

        // xl = hb@Wl + bl / xr = hb@Wr + br  (wave parity picks matrix)
        const unsigned short* WT   = ((w & 1) ? WRT : WLT) + c * 16384;
        const unsigned short* WAX  = wsb + 217088 + ((w & 1) ? 12288 : 0) + c * 2048;
        const float*          bias = ((w & 1) ? br : bl) + c * H;
        f32x4 acc[8] = {};
        f32x4 acce[2] = {};
        for (int kt = 0; kt < 4; ++kt) {
            f16x8 a0 = *reinterpret_cast<const f16x8*>(&hb[(m16)      * HSS + kt * 32 + kc * 8]);
            f16x8 a1 = *reinterpret_cast<const f16x8*>(&hb[(16 + m16) * HSS + kt * 32 + kc * 8]);
            #pragma unroll
            for (int i = 0; i < 4; ++i) {
                int nt = (w >> 1) * 4 + i;
                f16x8 b = *reinterpret_cast<const f16x8*>(&WT[(nt * 16 + m16) * 128 + kt * 32 + kc * 8]);
                acc[i]     = __builtin_amdgcn_mfma_f32_16x16x32_f16(a0, b, acc[i],     0, 0, 0);
                acc[4 + i] = __builtin_amdgcn_mfma_f32_16x16x32_f16(a1, b, acc[4 + i], 0, 0, 0);
            }
            if (w >= 2) {   // sl/sr tile: B row0 = W@att, rows 1-15 zero
                f16x8 bx = *reinterpret_cast<const f16x8*>(&WAX[m16 * 128 + kt * 32 + kc * 8]);
                acce[0] = __builtin_amdgcn_mfma_f32_16x16x32_f16(a0, bx, acce[0], 0, 0, 0);
                acce[1] = __builtin_amdgcn_mfma_f32_16x16x32_f16(a1, bx, acce[1], 0, 0, 0);
            }
        }
        {
            unsigned short* XO = (w & 1) ? xrb : xlb;
            const bool isL = !(w & 1);
            #pragma unroll
            for (int mt = 0; mt < 2; ++mt) {
                const bool live = !(mt == 1 && kc >= 2);   // rows >= 24
                if (live) {
                    #pragma unroll
                    for (int i = 0; i < 4; ++i) {
                        int col = (w >> 1) * 64 + i * 16 + m16;
                        float bv = bias[col];
                        unsigned short ub[4];
                        #pragma unroll
                        for (int r = 0; r < 4; ++r) {
                            int row = mt * 16 + kc * 4 + r;
                            ub[r] = f2h(acc[mt * 4 + i][r] + bv);
                            STPAIR(XO, row, col, ub[r]);
                        }
                        if (isL)
                            *reinterpret_cast<ushort4*>(&xlT[col * XTS + mt * 16 + kc * 4]) =
                                make_ushort4(ub[0], ub[1], ub[2], ub[3]);
                    }
                }
            }
            if (w >= 2 && m16 == 0) {       // col 0 of the slr tile = sl/sr
                float cst = (w == 2) ? wsf[c] : wsf[6 + c];
                float* dp = (w == 2) ? sn : (sn + 32);
                #pragma unroll
                for (int mt = 0; mt < 2; ++mt)
                #pragma unroll
                for (int r = 0; r < 4; ++r)
                    dp[mt * 16 + kc * 4 + r] = acce[mt][r] + cst;
            }
        }
        __syncthreads();

        // phase 2: per-edge logit + exp + scatter (unnormalized ex into Am)
        if (t < ESL) {
            const uint4* xa = reinterpret_cast<const uint4*>(&xlb[s_e * HSS]);
            const uint4* xb = reinterpret_cast<const uint4*>(&xrb[d_e * HSS]);
            const uint4* ap = reinterpret_cast<const uint4*>(ath);
            float a0 = 0.f, a1 = 0.f, a2 = 0.f, a3 = 0.f;
            #pragma unroll 4
            for (int cc = 0; cc < 16; ++cc) {
                uint4 wa = xa[cc], wb = xb[cc], pp = ap[cc];
                unsigned u0 = pkadd(wa.x, wb.x) & 0x7fff7fffu;
                unsigned u1 = pkadd(wa.y, wb.y) & 0x7fff7fffu;
                unsigned u2 = pkadd(wa.z, wb.z) & 0x7fff7fffu;
                unsigned u3 = pkadd(wa.w, wb.w) & 0x7fff7fffu;
                asm volatile("v_dot2_f32_f16 %0, %1, %2, %0" : "+v"(a0) : "v"(u0), "v"(pp.x));
                asm volatile("v_dot2_f32_f16 %0, %1, %2, %0" : "+v"(a1) : "v"(u1), "v"(pp.y));
                asm volatile("v_dot2_f32_f16 %0, %1, %2, %0" : "+v"(a2) : "v"(u2), "v"(pp.z));
                asm volatile("v_dot2_f32_f16 %0, %1, %2, %0" : "+v"(a3) : "v"(u3), "v"(pp.w));
            }
            float abss = (a0 + a1) + (a2 + a3);
            float lg = fmaf(0.6f, sn[s_e] + sn[32 + d_e], 0.4f * abss);
            atomicAdd(&Am[d_e * AMS + s_e], __expf(lg));
        }
        __syncthreads();

        // phase 3: aggregate hb = (rowscale(Am) @ xl) + cbias (+ LR except convs 2,5)
        {
            int arow = (w & 1) * 16 + m16;
            float4 u0, u1;
            if (arow < P) {
                u0 = *reinterpret_cast<const float4*>(&Am[arow * AMS + kc * 8]);
                u1 = *reinterpret_cast<const float4*>(&Am[arow * AMS + kc * 8 + 4]);
            } else {
                u0 = make_float4(0.f, 0.f, 0.f, 0.f);
                u1 = u0;
            }
            float rs = u0.x + u0.y + u0.z + u0.w + u1.x + u1.y + u1.z + u1.w;
            rs += __shfl_xor(rs, 16);
            rs += __shfl_xor(rs, 32);
            float sc = (arow < P) ? __builtin_amdgcn_rcpf(rs) : 0.f;
            f16x8 a;
            a[0] = (_Float16)(u0.x * sc); a[1] = (_Float16)(u0.y * sc);
            a[2] = (_Float16)(u0.z * sc); a[3] = (_Float16)(u0.w * sc);
            a[4] = (_Float16)(u1.x * sc); a[5] = (_Float16)(u1.y * sc);
            a[6] = (_Float16)(u1.z * sc); a[7] = (_Float16)(u1.w * sc);
            f32x4 acc2[4] = {};
            #pragma unroll
            for (int i = 0; i < 4; ++i) {
                int nt = (w >> 1) * 4 + i;
                f16x8 b = *reinterpret_cast<const f16x8*>(&xlT[(nt * 16 + m16) * XTS + kc * 8]);
                acc2[i] = __builtin_amdgcn_mfma_f32_16x16x32_f16(a, b, acc2[i], 0, 0, 0);
            }
            const bool doact = (c % 3) < 2;
            const bool live = !((w & 1) && kc >= 2);
            if (live) {
                #pragma unroll
                for (int i = 0; i < 4; ++i) {
                    int col = (w >> 1) * 64 + i * 16 + m16;
                    float cb = cbias[c * H + col];
                    #pragma unroll
                    for (int r = 0; r < 4; ++r) {
                        int row = (w & 1) * 16 + kc * 4 + r;
                        float v = acc2[i][r] + cb;
                        if (doact) v = lrelu(v, 0.01f);
                        unsigned short ub = f2h(v);
                        STPAIR(hb, row, col, ub);
                    }
                }
            }
        }
        __syncthreads();
    }

    // ---------------- pool + head MLP (f32, xlb region reused as scratch) ----
    float* scr = (float*)(LDSM + 6528);
    float* z  = scr;          // 136
    float* pa = scr + 144;
    float* pb = scr + 288;
    float* h1 = scr + 432;
    float* qa = scr + 576;
    float* qb = scr + 720;
    float* h2 = scr + 864;    // ends at 992 floats < 1632 available
    if (t < H) {
        float s = 0.f;
        for (int r = 0; r < P; ++r) s += h2f(hb[r * HSS + t]);
        z[t] = s;
    } else if (t < H + EX) {
        z[t] = extra[(long long)g * EX + (t - H)];
    }
    __syncthreads();
    {
        int j = t & 127, half = t >> 7;
        float a = half ? 0.f : bf0[j];
        int k0 = half ? 68 : 0, k1 = half ? 136 : 68;
        for (int k = k0; k < k1; ++k) a += z[k] * Wf0[k * H + j];
        (half ? pb : pa)[j] = a;
    }
    __syncthreads();
    if (t < H) h1[t] = lrelu(pa[t] + pb[t], 0.01f);
    __syncthreads();
    {
        int j = t & 127, half = t >> 7;
        float a = half ? 0.f : bf1[j];
        int k0 = half * 64, k1 = k0 + 64;
        for (int k = k0; k < k1; ++k) a += h1[k] * Wf1[k * H + j];
        (half ? qb : qa)[j] = a;
    }
    __syncthreads();
    if (t < H) h2[t] = lrelu(qa[t] + qb[t], 0.01f);
    __syncthreads();
    if (t < NOUT) {
        float a = bf2[t];
        for (int k = 0; k < H; ++k) a += h2[k] * Wf2[k * NOUT + t];
        out[(long long)g * NOUT + t] = a;
    }
}

extern "C" void kernel_launch(void* const* d_in, const int* in_sizes, int n_in,
                              void* d_out, int out_size, void* d_ws, size_t ws_size,
                              hipStream_t stream) {
    (void)in_sizes; (void)n_in; (void)out_size; (void)ws_size;
    const float* x     = (const float*)d_in[0];
    const int*   src   = (const int*)  d_in[1];
    const int*   dst   = (const int*)  d_in[2];
    const float* extra = (const float*)d_in[4];
    const float* W0    = (const float*)d_in[5];
    const float* b0    = (const float*)d_in[6];
    const float* W1    = (const float*)d_in[7];
    const float* b1    = (const float*)d_in[8];
    const float* Wl    = (const float*)d_in[9];
    const float* bl    = (const float*)d_in[10];
    const float* Wr    = (const float*)d_in[11];
    const float* br    = (const float*)d_in[12];
    const float* att   = (const float*)d_in[13];
    const float* cbias = (const float*)d_in[14];
    const float* Wf0   = (const float*)d_in[15];
    const float* bf0   = (const float*)d_in[16];
    const float* Wf1   = (const float*)d_in[17];
    const float* bf1   = (const float*)d_in[18];
    const float* Wf2   = (const float*)d_in[19];
    const float* bf2   = (const float*)d_in[20];
    unsigned short* wsb = (unsigned short*)d_ws;
    float* out = (float*)d_out;

    cvtw<<<945, 256, 0, stream>>>(W0, W1, Wl, Wr, att, bl, br, wsb);
    gat_all<<<NG, 256, 0, stream>>>(x, src, dst, extra, b0, b1, bl, br, att, cbias,
                                    Wf0, bf0, Wf1, bf1, Wf2, bf2, wsb, out);
}